// Round 9
// baseline (486.674 us; speedup 1.0000x reference)
//
#include <hip/hip_runtime.h>
#include <cstdint>
#include <cstddef>

// PatchAttention on MI355X — round 11:
//  - embed GEMM: direct-A hybrid. A fragments load straight from x (f32)
//    into per-lane regs (two named sets, 1-step pipeline), cvt in-reg; the
//    A LDS round-trip (HBM->reg->cvt->LDS->reg) is deleted — per-step LDS
//    traffic drops 3x (round-10 accounting: ds ops were the largest
//    per-step throughput term). B keeps a 2-buffer global_load_lds ring.
//    Counted-vmcnt asm barriers retained (they also PIN the reg loads in
//    their step — the round-8 load-sinking fix). LDS 48->16 KB.
//  - everything else identical to round 10.

typedef __bf16 bf16x8 __attribute__((ext_vector_type(8)));
typedef float f32x4 __attribute__((ext_vector_type(4)));
typedef unsigned short u16x4 __attribute__((ext_vector_type(4)));

__device__ __forceinline__ unsigned short f2bf(float f) {
  unsigned u = __builtin_bit_cast(unsigned, f);
  u += 0x7fffu + ((u >> 16) & 1u);  // round-to-nearest-even
  return (unsigned short)(u >> 16);
}
__device__ __forceinline__ float bf2f(unsigned short u) {
  return __builtin_bit_cast(float, ((unsigned)u) << 16);
}

// async 16B global -> LDS (wave-uniform base + lane*16 layout)
__device__ __forceinline__ void async_ld16(const void* g, void* l) {
  __builtin_amdgcn_global_load_lds(
      (const __attribute__((address_space(1))) void*)g,
      (__attribute__((address_space(3))) void*)l, 16, 0, 0);
}

__device__ __forceinline__ bf16x8 cvt8f(float4 a, float4 b) {
  unsigned short t[8] = {f2bf(a.x), f2bf(a.y), f2bf(a.z), f2bf(a.w),
                         f2bf(b.x), f2bf(b.y), f2bf(b.z), f2bf(b.w)};
  return *(const bf16x8*)t;
}

// ---------------------------------------------------------------------------
// RPE table: MLP(2 -> 512 -> 8) over the 63x63 grid -> tableT [8][4096] f32.
__global__ __launch_bounds__(256) void rpe_table_kernel(
    const float* __restrict__ w1, const float* __restrict__ b1,
    const float* __restrict__ w2, float* __restrict__ tableT) {
  int t = blockIdx.x * 256 + threadIdx.x;
  if (t >= 3969) return;
  int a = t / 63, c = t - a * 63;
  float rh = (float)(a - 31) * (1.0f / 31.0f);
  float rw = (float)(c - 31) * (1.0f / 31.0f);
  float acc[8];
#pragma unroll
  for (int h = 0; h < 8; h++) acc[h] = 0.f;
  for (int j = 0; j < 512; j++) {
    float hv = fmaxf(rh * w1[2 * j] + rw * w1[2 * j + 1] + b1[j], 0.f);
#pragma unroll
    for (int h = 0; h < 8; h++) acc[h] += hv * w2[h * 512 + j];
  }
#pragma unroll
  for (int h = 0; h < 8; h++) tableT[h * 4096 + t] = acc[h];
}

// ---------------------------------------------------------------------------
// generic fp32 -> bf16 convert, 8 elems/thread
__global__ __launch_bounds__(256) void cvt_bf16_kernel(
    const float* __restrict__ src, unsigned short* __restrict__ dst, int n8) {
  int i = blockIdx.x * 256 + threadIdx.x;
  if (i >= n8) return;
  const float4* s4 = (const float4*)src + (size_t)i * 2;
  float4 a = s4[0], b = s4[1];
  unsigned short t[8] = {f2bf(a.x), f2bf(a.y), f2bf(a.z), f2bf(a.w),
                         f2bf(b.x), f2bf(b.y), f2bf(b.z), f2bf(b.w)};
  *(uint4*)(dst + (size_t)i * 8) = *(const uint4*)t;
}

// transpose+convert: src [256][4096] f32 -> dst [4096][256] bf16
__global__ __launch_bounds__(256) void transpose_cvt_kernel(
    const float* __restrict__ src, unsigned short* __restrict__ dst) {
  __shared__ float tile[32][33];
  int bx = blockIdx.x;
  int by = blockIdx.y;
  int tx = threadIdx.x & 31, ty = threadIdx.x >> 5;
#pragma unroll
  for (int r = 0; r < 32; r += 8)
    tile[ty + r][tx] = src[(size_t)(by * 32 + ty + r) * 4096 + bx * 32 + tx];
  __syncthreads();
#pragma unroll
  for (int r = 0; r < 32; r += 8)
    dst[(size_t)(bx * 32 + ty + r) * 256 + by * 32 + tx] = f2bf(tile[tx][ty + r]);
}

// ---------------------------------------------------------------------------
// splitk reduce: out[8192*256] bf16 = sum_{s<NS} part[s][.] + bias[col]
template <int NS>
__global__ __launch_bounds__(256) void splitk_reduce_kernel(
    const float* __restrict__ part, const float* __restrict__ bias,
    unsigned short* __restrict__ out) {
  size_t i = ((size_t)blockIdx.x * 256 + threadIdx.x) * 8;
  const float4* p = (const float4*)(part + i);
  const size_t s4 = 2097152 / 4;  // float4 stride per split
  float4 a0 = p[0], a1 = p[1];
#pragma unroll
  for (int s = 1; s < NS; s++) {
    float4 b0 = p[s * s4], b1 = p[s * s4 + 1];
    a0.x += b0.x; a0.y += b0.y; a0.z += b0.z; a0.w += b0.w;
    a1.x += b1.x; a1.y += b1.y; a1.z += b1.z; a1.w += b1.w;
  }
  int col = (int)(i & 255);
  unsigned short t8[8] = {
      f2bf(a0.x + bias[col + 0]), f2bf(a0.y + bias[col + 1]),
      f2bf(a0.z + bias[col + 2]), f2bf(a0.w + bias[col + 3]),
      f2bf(a1.x + bias[col + 4]), f2bf(a1.y + bias[col + 5]),
      f2bf(a1.z + bias[col + 6]), f2bf(a1.w + bias[col + 7])};
  *(uint4*)(out + i) = *(const uint4*)t8;
}

// ---------------------------------------------------------------------------
// Embed GEMM, fused im2col, direct-A counted-vmcnt pipeline, split-K x4:
//   Cpart[z][8192][256] f32 = x-as-A[8192, z*1024 .. +1024] * wE^T
// Per k-step: {cvt aCur->af (auto-waits its x loads, already retired by the
// prior barrier); ds_read B frags; issue B(t+1) gll; load x(t+2)->aCur;
// MFMA; asm "vmcnt(8) lgkmcnt(0); s_barrier"} — retires x(t+1)+B(t+1),
// keeps x(t+2)'s 8 loads in flight across the barrier (~1.2 steps of HBM
// latency cover). No A LDS at all; Bs = 2 x 8 KB ring.
__global__ __launch_bounds__(256) void gemm_embed_kernel(
    const float* __restrict__ x, const unsigned short* __restrict__ Bw,
    float* __restrict__ Cpart) {
  __shared__ unsigned short Bs[2 * 4096];  // 16 KB
  int tid = threadIdx.x;
  int lane = tid & 63, wave = tid >> 6;

  int L = blockIdx.x;              // 0..511
  int xcd = L & 7, j = L >> 3;     // j 0..63
  int pair = xcd * 32 + (j >> 1);  // 0..255 (bijective)
  int n0 = (j & 1) * 128;
  int z = pair & 3, y = pair >> 2;
  int m0 = y * 128;
  int wm = (wave & 1) * 64, wn = (wave >> 1) * 64;
  int fr = lane & 15, fh = lane >> 4;

  f32x4 acc[4][4];
#pragma unroll
  for (int i = 0; i < 4; i++)
#pragma unroll
    for (int jj = 0; jj < 4; jj++) acc[i][jj] = (f32x4){0.f, 0.f, 0.f, 0.f};

  // B staging (bf16 weights [256][4096]) via global_load_lds, 2-buffer ring
  int f0 = tid, f1 = tid + 256;
  const unsigned short* Bg0 =
      Bw + (size_t)(n0 + (f0 >> 2)) * 4096 + z * 1024 + (f0 & 3) * 8;
  const unsigned short* Bg1 =
      Bw + (size_t)(n0 + (f1 >> 2)) * 4096 + z * 1024 + (f1 & 3) * 8;
  unsigned short* Bl0 = Bs + f0 * 8;
  unsigned short* Bl1 = Bs + f1 * 8;

  // direct-A: per-lane fragment pointers. frag tt = row m0+wm+tt*16+fr,
  // k = z*1024 + t*32 + fh*8 -> c = z*64 + 2t + (fh>>1), p0 = (2*fh)&3;
  // 8 k-values = two float4 rows (p0, p0+1) -> xp[tt][ax] and xp[tt][ax+32].
  const float4* x4 = (const float4*)x;
  int c0 = z * 64 + (fh >> 1);
  int p0 = (fh * 2) & 3;
  const float4* xp[4];
#pragma unroll
  for (int tt = 0; tt < 4; tt++) {
    int m = m0 + wm + tt * 16 + fr;
    int b_ = m >> 10, hp = (m >> 5) & 31, wp = m & 31;
    xp[tt] = x4 + (size_t)((b_ * 256 + c0) * 128 + hp * 4 + p0) * 32 + wp;
  }

  float4 aC[8], aN[8];  // two named x-tile register sets

  // ---- prologue: B(0) issued; x(0)->aC, x(1)->aN in flight ----
  async_ld16(Bg0, Bl0);
  async_ld16(Bg1, Bl1);
#pragma unroll
  for (int tt = 0; tt < 4; tt++) {
    aC[2 * tt] = xp[tt][0];
    aC[2 * tt + 1] = xp[tt][32];
  }
#pragma unroll
  for (int tt = 0; tt < 4; tt++) {
    aN[2 * tt] = xp[tt][8192];
    aN[2 * tt + 1] = xp[tt][8224];
  }
  // retire B(0) (queue: B0 x2, x0 x8, x1 x8 -> keep 16)
  asm volatile("s_waitcnt vmcnt(16) lgkmcnt(0)\n\ts_barrier" ::: "memory");

  auto step = [&](int t, float4 (&aCur)[8]) {
    // convert this step's A regs (their loads were retired by prior barrier)
    bf16x8 af[4];
#pragma unroll
    for (int tt = 0; tt < 4; tt++)
      af[tt] = cvt8f(aCur[2 * tt], aCur[2 * tt + 1]);
    // B frags from LDS
    const unsigned short* Bsc = Bs + ((t & 1) << 12);
    bf16x8 bfr[4];
#pragma unroll
    for (int tt = 0; tt < 4; tt++)
      bfr[tt] = *(const bf16x8*)(Bsc + (wn + tt * 16 + fr) * 32 + fh * 8);
    // issue B(t+1) into the other buffer (clamped source keeps count uniform)
    int tb = (t + 1 > 31) ? 31 : t + 1;
    async_ld16(Bg0 + (tb << 5), Bl0 + (((t + 1) & 1) << 12));
    async_ld16(Bg1 + (tb << 5), Bl1 + (((t + 1) & 1) << 12));
    // load x(t+2) into the register set just consumed by the cvt above
    int tc = (t + 2 > 31) ? 31 : t + 2;
    size_t ax = (size_t)tc * 8192;
#pragma unroll
    for (int tt = 0; tt < 4; tt++) {
      aCur[2 * tt] = xp[tt][ax];
      aCur[2 * tt + 1] = xp[tt][ax + 32];
    }
    __builtin_amdgcn_s_setprio(1);
#pragma unroll
    for (int mt = 0; mt < 4; mt++)
#pragma unroll
      for (int nt = 0; nt < 4; nt++)
        acc[mt][nt] = __builtin_amdgcn_mfma_f32_16x16x32_bf16(
            af[mt], bfr[nt], acc[mt][nt], 0, 0, 0);
    __builtin_amdgcn_s_setprio(0);
    // retire x(t+1)+B(t+1); keep x(t+2)'s 8 loads in flight across barrier
    asm volatile("s_waitcnt vmcnt(8) lgkmcnt(0)\n\ts_barrier" ::: "memory");
  };

  for (int it = 0; it < 16; it++) {
    step(2 * it, aC);
    step(2 * it + 1, aN);
  }

  // epilogue: f32 partials (C/D layout col = lane&15, row = (lane>>4)*4 + r)
  float* Cp = Cpart + (size_t)z * 2097152;
#pragma unroll
  for (int mt = 0; mt < 4; mt++) {
    int row0 = m0 + wm + mt * 16 + fh * 4;
#pragma unroll
    for (int nt = 0; nt < 4; nt++) {
      int col = n0 + wn + nt * 16 + fr;
#pragma unroll
      for (int r = 0; r < 4; r++)
        Cp[(size_t)(row0 + r) * 256 + col] = acc[mt][nt][r];
    }
  }
}

// ---------------------------------------------------------------------------
// bf16 MFMA GEMM: C[M,N] = A[M,K] * B^T (B given [N,K] bf16) + bias.
// CMODE: 1 = bf16 C, 2 = fused col2im into y[8,256,128,128] f32,
//        3 = fused QKV split, 4 = split-K f32 partials.
template <int CMODE>
__global__ __launch_bounds__(256) void gemm_mfma_kernel(
    const unsigned short* __restrict__ A, const unsigned short* __restrict__ B,
    const float* __restrict__ bias, void* __restrict__ Cv,
    int M, int N, int K, int lda, int ldb, int ldc) {
  __shared__ unsigned short As[2 * 128 * 32];
  __shared__ unsigned short Bs[2 * 128 * 32];
  int tid = threadIdx.x;
  int lane = tid & 63;
  int wave = tid >> 6;
  int m0 = blockIdx.y * 128, n0 = blockIdx.x * 128;
  int wm = (wave & 1) * 64, wn = (wave >> 1) * 64;

  if (CMODE == 4) {
    int s = blockIdx.z;
    A += (size_t)s * K;
    B += (size_t)s * K;
    Cv = (void*)((float*)Cv + (size_t)s * M * N);
  }

  f32x4 acc[4][4];
#pragma unroll
  for (int i = 0; i < 4; i++)
#pragma unroll
    for (int j = 0; j < 4; j++) acc[i][j] = (f32x4){0.f, 0.f, 0.f, 0.f};

  int f0 = tid, f1 = tid + 256;
  const unsigned short* Ag0 = A + (size_t)(m0 + (f0 >> 2)) * lda + (f0 & 3) * 8;
  const unsigned short* Ag1 = A + (size_t)(m0 + (f1 >> 2)) * lda + (f1 & 3) * 8;
  const unsigned short* Bg0 = B + (size_t)(n0 + (f0 >> 2)) * ldb + (f0 & 3) * 8;
  const unsigned short* Bg1 = B + (size_t)(n0 + (f1 >> 2)) * ldb + (f1 & 3) * 8;
  unsigned short* Al0 = As + f0 * 8;
  unsigned short* Al1 = As + f1 * 8;
  unsigned short* Bl0 = Bs + f0 * 8;
  unsigned short* Bl1 = Bs + f1 * 8;

  int fr = lane & 15;
  int fh = lane >> 4;

  int ntiles = K >> 5;
  async_ld16(Ag0, Al0);
  async_ld16(Ag1, Al1);
  async_ld16(Bg0, Bl0);
  async_ld16(Bg1, Bl1);
  __syncthreads();

  for (int t = 0; t < ntiles; t++) {
    int cur = (t & 1) << 12;
    int nxt = cur ^ 4096;
    if (t + 1 < ntiles) {
      int kn = (t + 1) << 5;
      async_ld16(Ag0 + kn, Al0 + nxt);
      async_ld16(Ag1 + kn, Al1 + nxt);
      async_ld16(Bg0 + kn, Bl0 + nxt);
      async_ld16(Bg1 + kn, Bl1 + nxt);
    }
    const unsigned short* Asc = As + cur;
    const unsigned short* Bsc = Bs + cur;
    bf16x8 af[4], bfr[4];
#pragma unroll
    for (int tt = 0; tt < 4; tt++) {
      af[tt] = *(const bf16x8*)(Asc + (wm + tt * 16 + fr) * 32 + fh * 8);
      bfr[tt] = *(const bf16x8*)(Bsc + (wn + tt * 16 + fr) * 32 + fh * 8);
    }
#pragma unroll
    for (int mt = 0; mt < 4; mt++)
#pragma unroll
      for (int nt = 0; nt < 4; nt++)
        acc[mt][nt] = __builtin_amdgcn_mfma_f32_16x16x32_bf16(
            af[mt], bfr[nt], acc[mt][nt], 0, 0, 0);
    __syncthreads();
  }

#pragma unroll
  for (int mt = 0; mt < 4; mt++) {
    int row0 = m0 + wm + mt * 16 + fh * 4;
    if (CMODE == 2) {
      int b = row0 >> 10, hp = (row0 >> 5) & 31, wp = row0 & 31;
      size_t rowoff0 = (size_t)b * 4194304 + hp * 512 + wp * 4;
      float* y = (float*)Cv;
#pragma unroll
      for (int nt = 0; nt < 4; nt++) {
        int col = n0 + wn + nt * 16 + fr;
        int o = col >> 4, p = (col >> 2) & 3, q = col & 3;
        size_t coloff = (size_t)o * 16384 + p * 128 + q;
        float bv = bias[o];
#pragma unroll
        for (int r = 0; r < 4; r++)
          y[rowoff0 + r * 4 + coloff] = acc[mt][nt][r] + bv;
      }
    } else if (CMODE == 3) {
      unsigned short* base = (unsigned short*)Cv;
#pragma unroll
      for (int nt = 0; nt < 4; nt++) {
        int col = n0 + wn + nt * 16 + fr;
        int which = col >> 8, hh = (col >> 5) & 7, d = col & 31;
        float bv = bias[col];
#pragma unroll
        for (int r = 0; r < 4; r++) {
          int row = row0 + r;
          int bb = row >> 10, nn = row & 1023;
          int bh = bb * 8 + hh;
          float v = acc[mt][nt][r] + bv;
          if (which == 0) v *= 0.17677669529663687f;  // 1/sqrt(32)
          size_t addr;
          if (which < 2)
            addr = (size_t)which * 2097152 + ((size_t)bh * 1024 + nn) * 32 + d;
          else
            addr = (size_t)2 * 2097152 + (size_t)bh * 32768 + (size_t)d * 1024 + nn;
          base[addr] = f2bf(v);
        }
      }
    } else if (CMODE == 4) {
      float* Cp = (float*)Cv;
#pragma unroll
      for (int nt = 0; nt < 4; nt++) {
        int col = n0 + wn + nt * 16 + fr;
#pragma unroll
        for (int r = 0; r < 4; r++)
          Cp[(size_t)(row0 + r) * ldc + col] = acc[mt][nt][r];
      }
    } else {
#pragma unroll
      for (int nt = 0; nt < 4; nt++) {
        int col = n0 + wn + nt * 16 + fr;
        float bv = bias ? bias[col] : 0.f;
        unsigned short* C = (unsigned short*)Cv;
#pragma unroll
        for (int r = 0; r < 4; r++)
          C[(size_t)(row0 + r) * ldc + col] = f2bf(acc[mt][nt][r] + bv);
      }
    }
  }
}

// ---------------------------------------------------------------------------
// MFMA flash attention — barrier-free, rolled 8x2 pipelined loop (round 7).
__global__ __launch_bounds__(512) void attn_mfma_kernel(
    const unsigned short* __restrict__ Qb, const unsigned short* __restrict__ Kb,
    const unsigned short* __restrict__ Vtb,
    const float* __restrict__ tableT,
    unsigned short* __restrict__ out) {
  __shared__ float th[3972];                 // per-head RPE table column
  __shared__ unsigned short Ps[2][8][1088];  // [half][wave][16*68] P scratch

  int tid = threadIdx.x;
  int lane = tid & 63, w = tid >> 6;
  int n = lane & 15, g = lane >> 4;
  int blk = blockIdx.x;
  int h = blk & 7, b = (blk >> 3) & 7, qt = blk >> 6;
  int bh = b * 8 + h;
  int q0 = qt * 128;

  const unsigned short* Qg = Qb + ((size_t)bh * 1024 + q0) * 32;
  const unsigned short* Kg = Kb + (size_t)bh * 1024 * 32;
  const unsigned short* Vg = Vtb + (size_t)bh * 32 * 1024;
  const float* tg = tableT + (size_t)h * 4096;

  for (int i = tid; i < 3969; i += 512) th[i] = tg[i];
  bf16x8 qf = *(const bf16x8*)(Qg + (size_t)(w * 16 + n) * 32 + g * 8);
  __syncthreads();  // table ready — the only barrier

  f32x4 oacc[2];
  oacc[0] = (f32x4){0.f, 0.f, 0.f, 0.f};
  oacc[1] = (f32x4){0.f, 0.f, 0.f, 0.f};
  float m_run = -1e30f, l_run = 0.f;  // l_run g-partial, reduced at end

  int q = q0 + w * 16 + n;
  int tbase = (q >> 5) * 63 + (q & 31) + 1984;  // + (31*63+31)

  unsigned short* PwA = &Ps[0][w][0];
  unsigned short* PwB = &Ps[1][w][0];

  bf16x8 kfA[4], kfB[4];
#pragma unroll
  for (int mt = 0; mt < 4; mt++)
    kfA[mt] = *(const bf16x8*)(Kg + (size_t)(mt * 16 + n) * 32 + g * 8);

  auto half_step = [&](const bf16x8 (&kf)[4], int k0, unsigned short* Pw) {
    bf16x8 vf[4];
#pragma unroll
    for (int i = 0; i < 4; i++)
      vf[i] = *(const bf16x8*)(Vg + (size_t)((i & 1) * 16 + n) * 1024 + k0 +
                               (i >> 1) * 32 + g * 8);

    f32x4 s[4];
    __builtin_amdgcn_s_setprio(1);
#pragma unroll
    for (int mt = 0; mt < 4; mt++)
      s[mt] = __builtin_amdgcn_mfma_f32_16x16x32_bf16(
          kf[mt], qf, (f32x4){0.f, 0.f, 0.f, 0.f}, 0, 0, 0);
    __builtin_amdgcn_s_setprio(0);

#pragma unroll
    for (int mt = 0; mt < 4; mt++) {
      int kb = k0 + mt * 16 + g * 4;
      int ib = tbase - (kb >> 5) * 63 - (kb & 31);
      s[mt][0] += th[ib];
      s[mt][1] += th[ib - 1];
      s[mt][2] += th[ib - 2];
      s[mt][3] += th[ib - 3];
    }

    float mx = -1e30f;
#pragma unroll
    for (int mt = 0; mt < 4; mt++)
#pragma unroll
      for (int r = 0; r < 4; r++) mx = fmaxf(mx, s[mt][r]);
    mx = fmaxf(mx, __shfl_xor(mx, 16, 64));
    mx = fmaxf(mx, __shfl_xor(mx, 32, 64));
    float m_new = fmaxf(m_run, mx);
    float alpha = __expf(m_run - m_new);
    m_run = m_new;

    float ls = 0.f;
#pragma unroll
    for (int mt = 0; mt < 4; mt++) {
#pragma unroll
      for (int r = 0; r < 4; r++) {
        float p = __expf(s[mt][r] - m_new);
        s[mt][r] = p;
        ls += p;
      }
      u16x4 pk = {f2bf(s[mt][0]), f2bf(s[mt][1]), f2bf(s[mt][2]),
                  f2bf(s[mt][3])};
      *(u16x4*)(Pw + n * 68 + mt * 16 + g * 4) = pk;
    }
    l_run = l_run * alpha + ls;

#pragma unroll
    for (int dt = 0; dt < 2; dt++)
#pragma unroll
      for (int r = 0; r < 4; r++) oacc[dt][r] *= alpha;
    __builtin_amdgcn_s_setprio(1);
#pragma unroll
    for (int kt = 0; kt < 2; kt++) {
      bf16x8 pf = *(const bf16x8*)(Pw + n * 68 + kt * 32 + g * 8);
      oacc[0] = __builtin_amdgcn_mfma_f32_16x16x32_bf16(vf[kt * 2 + 0], pf,
                                                        oacc[0], 0, 0, 0);
      oacc[1] = __builtin_amdgcn_mfma_f32_16x16x32_bf16(vf[kt * 2 + 1], pf,
                                                        oacc[1], 0, 0, 0);
    }
    __builtin_amdgcn_s_setprio(0);
  };

  for (int tt = 0; tt < 8; tt++) {
    int k0 = tt * 128;
#pragma unroll
    for (int mt = 0; mt < 4; mt++)
      kfB[mt] = *(const bf16x8*)(Kg + (size_t)(k0 + 64 + mt * 16 + n) * 32 +
                                 g * 8);
    half_step(kfA, k0, PwA);
    if (tt < 7) {
#pragma unroll
      for (int mt = 0; mt < 4; mt++)
        kfA[mt] = *(const bf16x8*)(Kg + (size_t)(k0 + 128 + mt * 16 + n) * 32 +
                                   g * 8);
    }
    half_step(kfB, k0 + 64, PwB);
  }

  float l = l_run;
  l += __shfl_xor(l, 16, 64);
  l += __shfl_xor(l, 32, 64);
  float invl = 1.f / l;
  unsigned short* ob = out + ((size_t)(b * 1024 + q) * 256) + h * 32;
#pragma unroll
  for (int dt = 0; dt < 2; dt++) {
    u16x4 o4 = {f2bf(oacc[dt][0] * invl), f2bf(oacc[dt][1] * invl),
                f2bf(oacc[dt][2] * invl), f2bf(oacc[dt][3] * invl)};
    *(u16x4*)(ob + dt * 16 + g * 4) = o4;
  }
}

// ---------------------------------------------------------------------------
extern "C" void kernel_launch(void* const* d_in, const int* in_sizes, int n_in,
                              void* d_out, int out_size, void* d_ws, size_t ws_size,
                              hipStream_t stream) {
  const float* x         = (const float*)d_in[0];
  const float* w_embed   = (const float*)d_in[1];
  const float* b_embed   = (const float*)d_in[2];
  const float* cpb_w1    = (const float*)d_in[3];
  const float* cpb_b1    = (const float*)d_in[4];
  const float* cpb_w2    = (const float*)d_in[5];
  const float* w_qkv     = (const float*)d_in[6];
  const float* b_qkv     = (const float*)d_in[7];
  const float* w_proj    = (const float*)d_in[8];
  const float* b_proj    = (const float*)d_in[9];
  const float* w_unembed = (const float*)d_in[10];
  const float* b_unembed = (const float*)d_in[11];
  float* out = (float*)d_out;

  // workspace layout
  char* w = (char*)d_ws;
  float*          ProjP = (float*)w;          w += (size_t)8388608 * 4;      // 32 MB (proj partials)
  unsigned short* tok   = (unsigned short*)w; w += (size_t)8192 * 256 * 2;   //  4 MB
  unsigned short* wE    = (unsigned short*)w; w += (size_t)1048576 * 2;      //  2 MB
  unsigned short* wQ    = (unsigned short*)w; w += (size_t)196608 * 2;       // 384 KB
  unsigned short* wP    = (unsigned short*)w; w += (size_t)65536 * 2;        // 128 KB
  unsigned short* wUt   = (unsigned short*)w; w += (size_t)1048576 * 2;      //  2 MB
  float*          tableT= (float*)w;          w += (size_t)32768 * 4;        // 128 KB
  float*          PART  = (float*)w;          w += (size_t)4 * 2097152 * 4;  // 32 MB (embed partials x4)

  // live-range aliases inside PART (embed partials dead once reduced):
  unsigned short* qkvB  = (unsigned short*)PART;                     // 12 MB
  unsigned short* attno = (unsigned short*)((char*)PART + 12582912); //  4 MB
  unsigned short* z2    = (unsigned short*)((char*)PART + 16777216); //  4 MB
  unsigned short* Qb  = qkvB;
  unsigned short* Kb  = qkvB + 2097152;
  unsigned short* Vtb = qkvB + 2 * 2097152;

  // ---- prep (weights, RPE table) ----
  cvt_bf16_kernel<<<512, 256, 0, stream>>>(w_embed, wE, 131072);
  cvt_bf16_kernel<<<96, 256, 0, stream>>>(w_qkv, wQ, 24576);
  cvt_bf16_kernel<<<32, 256, 0, stream>>>(w_proj, wP, 8192);
  transpose_cvt_kernel<<<dim3(128, 8), 256, 0, stream>>>(w_unembed, wUt);
  rpe_table_kernel<<<16, 256, 0, stream>>>(cpb_w1, cpb_b1, cpb_w2, tableT);

  // ---- embed: direct-A counted-vmcnt split-K x4 -> reduce -> tok ----
  gemm_embed_kernel<<<512, 256, 0, stream>>>(x, wE, PART);
  splitk_reduce_kernel<4><<<1024, 256, 0, stream>>>(PART, b_embed, tok);

  // ---- qkv + fused split/scale/transpose into Qb/Kb/Vtb ----
  gemm_mfma_kernel<3><<<dim3(6, 64), 256, 0, stream>>>(
      tok, wQ, b_qkv, qkvB, 8192, 768, 256, 256, 256, 0);

  // ---- attention (barrier-free, rolled 8x2) ----
  attn_mfma_kernel<<<512, 512, 0, stream>>>(Qb, Kb, Vtb, tableT, attno);

  // ---- proj: split-K x4 -> reduce -> z2 ----
  gemm_mfma_kernel<4><<<dim3(2, 64, 4), 256, 0, stream>>>(
      attno, wP, nullptr, ProjP, 8192, 256, 64, 256, 256, 256);
  splitk_reduce_kernel<4><<<1024, 256, 0, stream>>>(ProjP, b_proj, z2);

  // ---- unembed + fused col2im ----
  gemm_mfma_kernel<2><<<dim3(32, 64), 256, 0, stream>>>(
      z2, wUt, b_unembed, out, 8192, 4096, 256, 256, 256, 0);
}

// Round 10
// 470.598 us; speedup vs baseline: 1.0342x; 1.0342x over previous
//
#include <hip/hip_runtime.h>
#include <cstdint>
#include <cstddef>

// PatchAttention on MI355X — round 12:
//  - embed: 2-step-deep direct-A prefetch (3 named reg sets + 3-buffer B
//    ring, vmcnt(18) counted barriers; B(t+2) issued BEFORE x(t+3) so the
//    counted retire keeps 2 x-tiles in flight).
//  - proj GEMM deleted: folded into unembed via Wc = wUt@wProj^T and bias
//    bc (precomputed).  unembed runs on attno directly.
//  - all prep (cvt x2, transpose x2, RPE MLP, bc) merged into ONE kernel.
//  - attn: defer-max (T13) — skip O/l rescale when __all(mx<=m_run+8).

typedef __bf16 bf16x8 __attribute__((ext_vector_type(8)));
typedef float f32x4 __attribute__((ext_vector_type(4)));
typedef unsigned short u16x4 __attribute__((ext_vector_type(4)));

__device__ __forceinline__ unsigned short f2bf(float f) {
  unsigned u = __builtin_bit_cast(unsigned, f);
  u += 0x7fffu + ((u >> 16) & 1u);  // round-to-nearest-even
  return (unsigned short)(u >> 16);
}

// async 16B global -> LDS (wave-uniform base + lane*16 layout)
__device__ __forceinline__ void async_ld16(const void* g, void* l) {
  __builtin_amdgcn_global_load_lds(
      (const __attribute__((address_space(1))) void*)g,
      (__attribute__((address_space(3))) void*)l, 16, 0, 0);
}

__device__ __forceinline__ bf16x8 cvt8f(float4 a, float4 b) {
  unsigned short t[8] = {f2bf(a.x), f2bf(a.y), f2bf(a.z), f2bf(a.w),
                         f2bf(b.x), f2bf(b.y), f2bf(b.z), f2bf(b.w)};
  return *(const bf16x8*)t;
}

// ---------------------------------------------------------------------------
// Merged prep kernel. Block ranges:
//   [0,512)     cvt w_embed  f32->bf16 (wE)
//   [512,608)   cvt w_qkv    f32->bf16 (wQ)
//   [608,1632)  transpose+cvt w_unembed [256][4096] -> wUt [4096][256]
//   [1632,1696) transpose+cvt w_proj    [256][256]  -> wPT [256][256]
//   [1696,1712) RPE MLP -> tableT [8][4096]
//   [1712,1728) bc[j] = sum_c b_proj[c]*w_unembed[c][j] + b_unembed[j>>4]
__global__ __launch_bounds__(256) void prep_kernel(
    const float* __restrict__ w_embed, const float* __restrict__ w_qkv,
    const float* __restrict__ w_unembed, const float* __restrict__ w_proj,
    const float* __restrict__ cpb_w1, const float* __restrict__ cpb_b1,
    const float* __restrict__ cpb_w2, const float* __restrict__ b_proj,
    const float* __restrict__ b_unembed,
    unsigned short* __restrict__ wE, unsigned short* __restrict__ wQ,
    unsigned short* __restrict__ wUt, unsigned short* __restrict__ wPT,
    float* __restrict__ tableT, float* __restrict__ bc) {
  __shared__ float tile[32][33];
  int bx = blockIdx.x, tid = threadIdx.x;

  if (bx < 608) {  // plain cvt
    const float* src = (bx < 512) ? w_embed : w_qkv;
    unsigned short* dst = (bx < 512) ? wE : wQ;
    int i = (bx < 512) ? bx * 256 + tid : (bx - 512) * 256 + tid;
    const float4* s4 = (const float4*)src + (size_t)i * 2;
    float4 a = s4[0], b = s4[1];
    unsigned short t[8] = {f2bf(a.x), f2bf(a.y), f2bf(a.z), f2bf(a.w),
                           f2bf(b.x), f2bf(b.y), f2bf(b.z), f2bf(b.w)};
    *(uint4*)(dst + (size_t)i * 8) = *(const uint4*)t;
  } else if (bx < 1696) {  // transpose+cvt: src[R=256][C] -> dst[C][256]
    const float* src;
    unsigned short* dst;
    int C, bx2, by2;
    if (bx < 1632) {
      src = w_unembed; dst = wUt; C = 4096;
      int idx = bx - 608; bx2 = idx & 127; by2 = idx >> 7;
    } else {
      src = w_proj; dst = wPT; C = 256;
      int idx = bx - 1632; bx2 = idx & 7; by2 = idx >> 3;
    }
    int tx = tid & 31, ty = tid >> 5;
#pragma unroll
    for (int r = 0; r < 32; r += 8)
      tile[ty + r][tx] = src[(size_t)(by2 * 32 + ty + r) * C + bx2 * 32 + tx];
    __syncthreads();
#pragma unroll
    for (int r = 0; r < 32; r += 8)
      dst[(size_t)(bx2 * 32 + ty + r) * 256 + by2 * 32 + tx] =
          f2bf(tile[tx][ty + r]);
  } else if (bx < 1712) {  // RPE MLP
    int t = (bx - 1696) * 256 + tid;
    if (t >= 3969) return;
    int a = t / 63, c = t - a * 63;
    float rh = (float)(a - 31) * (1.0f / 31.0f);
    float rw = (float)(c - 31) * (1.0f / 31.0f);
    float acc[8];
#pragma unroll
    for (int h = 0; h < 8; h++) acc[h] = 0.f;
    for (int j = 0; j < 512; j++) {
      float hv = fmaxf(rh * cpb_w1[2 * j] + rw * cpb_w1[2 * j + 1] + cpb_b1[j],
                       0.f);
#pragma unroll
      for (int h = 0; h < 8; h++) acc[h] += hv * cpb_w2[h * 512 + j];
    }
#pragma unroll
    for (int h = 0; h < 8; h++) tableT[h * 4096 + t] = acc[h];
  } else {  // bc
    int j = (bx - 1712) * 256 + tid;
    float s = 0.f;
#pragma unroll 4
    for (int c = 0; c < 256; c++) s += b_proj[c] * w_unembed[(size_t)c * 4096 + j];
    bc[j] = s + b_unembed[j >> 4];
  }
}

// ---------------------------------------------------------------------------
// splitk reduce: out[8192*256] bf16 = sum_{s<NS} part[s][.] + bias[col]
template <int NS>
__global__ __launch_bounds__(256) void splitk_reduce_kernel(
    const float* __restrict__ part, const float* __restrict__ bias,
    unsigned short* __restrict__ out) {
  size_t i = ((size_t)blockIdx.x * 256 + threadIdx.x) * 8;
  const float4* p = (const float4*)(part + i);
  const size_t s4 = 2097152 / 4;  // float4 stride per split
  float4 a0 = p[0], a1 = p[1];
#pragma unroll
  for (int s = 1; s < NS; s++) {
    float4 b0 = p[s * s4], b1 = p[s * s4 + 1];
    a0.x += b0.x; a0.y += b0.y; a0.z += b0.z; a0.w += b0.w;
    a1.x += b1.x; a1.y += b1.y; a1.z += b1.z; a1.w += b1.w;
  }
  int col = (int)(i & 255);
  unsigned short t8[8] = {
      f2bf(a0.x + bias[col + 0]), f2bf(a0.y + bias[col + 1]),
      f2bf(a0.z + bias[col + 2]), f2bf(a0.w + bias[col + 3]),
      f2bf(a1.x + bias[col + 4]), f2bf(a1.y + bias[col + 5]),
      f2bf(a1.z + bias[col + 6]), f2bf(a1.w + bias[col + 7])};
  *(uint4*)(out + i) = *(const uint4*)t8;
}

// ---------------------------------------------------------------------------
// Embed GEMM, fused im2col, 2-deep direct-A counted-vmcnt pipeline, splitK x4:
//   Cpart[z][8192][256] f32 = x-as-A[8192, z*1024 .. +1024] * wE^T
// Per step t: {cvt x(t) regs -> af; ds_read B(t); issue B(t+2) (3-ring,
// BEFORE x so the counted retire order works); issue x(t+3) into the set
// just consumed; MFMA; "s_waitcnt vmcnt(18); s_barrier"}.  The barrier
// retires exactly x(t+1)+B(t+1); x(t+2),x(t+3),B(t+2) stay in flight ->
// ~2 k-steps of HBM latency cover.
__global__ __launch_bounds__(256) void gemm_embed_kernel(
    const float* __restrict__ x, const unsigned short* __restrict__ Bw,
    float* __restrict__ Cpart) {
  __shared__ unsigned short Bs[3 * 4096];  // 24 KB
  int tid = threadIdx.x;
  int lane = tid & 63, wave = tid >> 6;

  int L = blockIdx.x;              // 0..511
  int xcd = L & 7, j = L >> 3;     // j 0..63
  int pair = xcd * 32 + (j >> 1);  // 0..255 (bijective)
  int n0 = (j & 1) * 128;
  int z = pair & 3, y = pair >> 2;
  int m0 = y * 128;
  int wm = (wave & 1) * 64, wn = (wave >> 1) * 64;
  int fr = lane & 15, fh = lane >> 4;

  f32x4 acc[4][4];
#pragma unroll
  for (int i = 0; i < 4; i++)
#pragma unroll
    for (int jj = 0; jj < 4; jj++) acc[i][jj] = (f32x4){0.f, 0.f, 0.f, 0.f};

  // B staging (bf16 weights [256][4096]) via global_load_lds, 3-buffer ring
  int f0 = tid, f1 = tid + 256;
  const unsigned short* Bg0 =
      Bw + (size_t)(n0 + (f0 >> 2)) * 4096 + z * 1024 + (f0 & 3) * 8;
  const unsigned short* Bg1 =
      Bw + (size_t)(n0 + (f1 >> 2)) * 4096 + z * 1024 + (f1 & 3) * 8;
  unsigned short* Bl0 = Bs + f0 * 8;
  unsigned short* Bl1 = Bs + f1 * 8;

  // direct-A per-lane fragment pointers (frag tt = row m0+wm+tt*16+fr,
  // k-chunk fh*8 -> c = z*64 + 2t + (fh>>1), rows p0, p0+1)
  const float4* x4 = (const float4*)x;
  int c0 = z * 64 + (fh >> 1);
  int p0 = (fh * 2) & 3;
  const float4* xp[4];
#pragma unroll
  for (int tt = 0; tt < 4; tt++) {
    int m = m0 + wm + tt * 16 + fr;
    int b_ = m >> 10, hp = (m >> 5) & 31, wp = m & 31;
    xp[tt] = x4 + (size_t)((b_ * 256 + c0) * 128 + hp * 4 + p0) * 32 + wp;
  }

  float4 aA[8], aB[8], aC[8];  // three named x-tile register sets

#define LOADX(areg, T)                                  \
  {                                                     \
    size_t ax_ = (size_t)(T)*8192;                      \
    _Pragma("unroll") for (int tt = 0; tt < 4; tt++) {  \
      areg[2 * tt] = xp[tt][ax_];                       \
      areg[2 * tt + 1] = xp[tt][ax_ + 32];              \
    }                                                   \
  }

  // ---- prologue: pending after barrier = {x(1),B(1),x(2)} = 18 ----
  async_ld16(Bg0, Bl0);                 // B(0) -> ring 0
  async_ld16(Bg1, Bl1);
  LOADX(aA, 0);
  asm volatile("" ::: "memory");        // pin group order
  async_ld16(Bg0 + 32, Bl0 + 4096);     // B(1) -> ring 1
  async_ld16(Bg1 + 32, Bl1 + 4096);
  LOADX(aB, 1);
  asm volatile("" ::: "memory");
  LOADX(aC, 2);
  asm volatile("s_waitcnt vmcnt(18) lgkmcnt(0)\n\ts_barrier" ::: "memory");

  auto step = [&](int t, float4 (&aCur)[8]) {
    bf16x8 af[4];
#pragma unroll
    for (int tt = 0; tt < 4; tt++)
      af[tt] = cvt8f(aCur[2 * tt], aCur[2 * tt + 1]);
    const unsigned short* Bsc = Bs + (t % 3) * 4096;
    bf16x8 bfr[4];
#pragma unroll
    for (int tt = 0; tt < 4; tt++)
      bfr[tt] = *(const bf16x8*)(Bsc + (wn + tt * 16 + fr) * 32 + fh * 8);
    // issue B(t+2) FIRST (ring slot (t+2)%3), then x(t+3) (clamped tail
    // re-issues keep the 10-ops/step vmcnt arithmetic uniform)
    int tb = (t + 2 > 31) ? 31 : t + 2;
    async_ld16(Bg0 + (tb << 5), Bl0 + (tb % 3) * 4096);
    async_ld16(Bg1 + (tb << 5), Bl1 + (tb % 3) * 4096);
    asm volatile("" ::: "memory");
    int tc = (t + 3 > 31) ? 31 : t + 3;
    LOADX(aCur, tc);
    __builtin_amdgcn_s_setprio(1);
#pragma unroll
    for (int mt = 0; mt < 4; mt++)
#pragma unroll
      for (int nt = 0; nt < 4; nt++)
        acc[mt][nt] = __builtin_amdgcn_mfma_f32_16x16x32_bf16(
            af[mt], bfr[nt], acc[mt][nt], 0, 0, 0);
    __builtin_amdgcn_s_setprio(0);
    asm volatile("s_waitcnt vmcnt(18) lgkmcnt(0)\n\ts_barrier" ::: "memory");
  };

  for (int it = 0; it < 10; it++) {
    step(3 * it + 0, aA);
    step(3 * it + 1, aB);
    step(3 * it + 2, aC);
  }
  step(30, aA);
  step(31, aB);
#undef LOADX

  // epilogue: f32 partials (C/D layout col = lane&15, row = (lane>>4)*4 + r)
  float* Cp = Cpart + (size_t)z * 2097152;
#pragma unroll
  for (int mt = 0; mt < 4; mt++) {
    int row0 = m0 + wm + mt * 16 + fh * 4;
#pragma unroll
    for (int nt = 0; nt < 4; nt++) {
      int col = n0 + wn + nt * 16 + fr;
#pragma unroll
      for (int r = 0; r < 4; r++)
        Cp[(size_t)(row0 + r) * 256 + col] = acc[mt][nt][r];
    }
  }
}

// ---------------------------------------------------------------------------
// bf16 MFMA GEMM: C[M,N] = A[M,K] * B^T (B given [N,K] bf16) + bias.
// CMODE: 1 = bf16 C, 2 = fused col2im into y[8,256,128,128] f32 with
//        per-COLUMN bias (bc[4096], includes folded proj+unembed biases),
//        3 = fused QKV split, 4 = split-K f32 partials.
template <int CMODE>
__global__ __launch_bounds__(256) void gemm_mfma_kernel(
    const unsigned short* __restrict__ A, const unsigned short* __restrict__ B,
    const float* __restrict__ bias, void* __restrict__ Cv,
    int M, int N, int K, int lda, int ldb, int ldc) {
  __shared__ unsigned short As[2 * 128 * 32];
  __shared__ unsigned short Bs[2 * 128 * 32];
  int tid = threadIdx.x;
  int lane = tid & 63;
  int wave = tid >> 6;
  int m0 = blockIdx.y * 128, n0 = blockIdx.x * 128;
  int wm = (wave & 1) * 64, wn = (wave >> 1) * 64;

  if (CMODE == 4) {
    int s = blockIdx.z;
    A += (size_t)s * K;
    B += (size_t)s * K;
    Cv = (void*)((float*)Cv + (size_t)s * M * N);
  }

  f32x4 acc[4][4];
#pragma unroll
  for (int i = 0; i < 4; i++)
#pragma unroll
    for (int j = 0; j < 4; j++) acc[i][j] = (f32x4){0.f, 0.f, 0.f, 0.f};

  int f0 = tid, f1 = tid + 256;
  const unsigned short* Ag0 = A + (size_t)(m0 + (f0 >> 2)) * lda + (f0 & 3) * 8;
  const unsigned short* Ag1 = A + (size_t)(m0 + (f1 >> 2)) * lda + (f1 & 3) * 8;
  const unsigned short* Bg0 = B + (size_t)(n0 + (f0 >> 2)) * ldb + (f0 & 3) * 8;
  const unsigned short* Bg1 = B + (size_t)(n0 + (f1 >> 2)) * ldb + (f1 & 3) * 8;
  unsigned short* Al0 = As + f0 * 8;
  unsigned short* Al1 = As + f1 * 8;
  unsigned short* Bl0 = Bs + f0 * 8;
  unsigned short* Bl1 = Bs + f1 * 8;

  int fr = lane & 15;
  int fh = lane >> 4;

  int ntiles = K >> 5;
  async_ld16(Ag0, Al0);
  async_ld16(Ag1, Al1);
  async_ld16(Bg0, Bl0);
  async_ld16(Bg1, Bl1);
  __syncthreads();

  for (int t = 0; t < ntiles; t++) {
    int cur = (t & 1) << 12;
    int nxt = cur ^ 4096;
    if (t + 1 < ntiles) {
      int kn = (t + 1) << 5;
      async_ld16(Ag0 + kn, Al0 + nxt);
      async_ld16(Ag1 + kn, Al1 + nxt);
      async_ld16(Bg0 + kn, Bl0 + nxt);
      async_ld16(Bg1 + kn, Bl1 + nxt);
    }
    const unsigned short* Asc = As + cur;
    const unsigned short* Bsc = Bs + cur;
    bf16x8 af[4], bfr[4];
#pragma unroll
    for (int tt = 0; tt < 4; tt++) {
      af[tt] = *(const bf16x8*)(Asc + (wm + tt * 16 + fr) * 32 + fh * 8);
      bfr[tt] = *(const bf16x8*)(Bsc + (wn + tt * 16 + fr) * 32 + fh * 8);
    }
#pragma unroll
    for (int mt = 0; mt < 4; mt++)
#pragma unroll
      for (int nt = 0; nt < 4; nt++)
        acc[mt][nt] = __builtin_amdgcn_mfma_f32_16x16x32_bf16(
            af[mt], bfr[nt], acc[mt][nt], 0, 0, 0);
    __syncthreads();
  }

#pragma unroll
  for (int mt = 0; mt < 4; mt++) {
    int row0 = m0 + wm + mt * 16 + fh * 4;
    if (CMODE == 2) {
      int b = row0 >> 10, hp = (row0 >> 5) & 31, wp = row0 & 31;
      size_t rowoff0 = (size_t)b * 4194304 + hp * 512 + wp * 4;
      float* y = (float*)Cv;
#pragma unroll
      for (int nt = 0; nt < 4; nt++) {
        int col = n0 + wn + nt * 16 + fr;
        int o = col >> 4, p = (col >> 2) & 3, q = col & 3;
        size_t coloff = (size_t)o * 16384 + p * 128 + q;
        float bv = bias[col];  // bc: per-column folded proj+unembed bias
#pragma unroll
        for (int r = 0; r < 4; r++)
          y[rowoff0 + r * 4 + coloff] = acc[mt][nt][r] + bv;
      }
    } else if (CMODE == 3) {
      unsigned short* base = (unsigned short*)Cv;
#pragma unroll
      for (int nt = 0; nt < 4; nt++) {
        int col = n0 + wn + nt * 16 + fr;
        int which = col >> 8, hh = (col >> 5) & 7, d = col & 31;
        float bv = bias[col];
#pragma unroll
        for (int r = 0; r < 4; r++) {
          int row = row0 + r;
          int bb = row >> 10, nn = row & 1023;
          int bh = bb * 8 + hh;
          float v = acc[mt][nt][r] + bv;
          if (which == 0) v *= 0.17677669529663687f;  // 1/sqrt(32)
          size_t addr;
          if (which < 2)
            addr = (size_t)which * 2097152 + ((size_t)bh * 1024 + nn) * 32 + d;
          else
            addr = (size_t)2 * 2097152 + (size_t)bh * 32768 + (size_t)d * 1024 + nn;
          base[addr] = f2bf(v);
        }
      }
    } else if (CMODE == 4) {
      float* Cp = (float*)Cv;
#pragma unroll
      for (int nt = 0; nt < 4; nt++) {
        int col = n0 + wn + nt * 16 + fr;
#pragma unroll
        for (int r = 0; r < 4; r++)
          Cp[(size_t)(row0 + r) * ldc + col] = acc[mt][nt][r];
      }
    } else {
#pragma unroll
      for (int nt = 0; nt < 4; nt++) {
        int col = n0 + wn + nt * 16 + fr;
        float bv = bias ? bias[col] : 0.f;
        unsigned short* C = (unsigned short*)Cv;
#pragma unroll
        for (int r = 0; r < 4; r++)
          C[(size_t)(row0 + r) * ldc + col] = f2bf(acc[mt][nt][r] + bv);
      }
    }
  }
}

// ---------------------------------------------------------------------------
// MFMA flash attention — barrier-free, rolled 8x2 pipeline + defer-max (T13).
__global__ __launch_bounds__(512) void attn_mfma_kernel(
    const unsigned short* __restrict__ Qb, const unsigned short* __restrict__ Kb,
    const unsigned short* __restrict__ Vtb,
    const float* __restrict__ tableT,
    unsigned short* __restrict__ out) {
  __shared__ float th[3972];                 // per-head RPE table column
  __shared__ unsigned short Ps[2][8][1088];  // [half][wave][16*68] P scratch

  int tid = threadIdx.x;
  int lane = tid & 63, w = tid >> 6;
  int n = lane & 15, g = lane >> 4;
  int blk = blockIdx.x;
  int h = blk & 7, b = (blk >> 3) & 7, qt = blk >> 6;
  int bh = b * 8 + h;
  int q0 = qt * 128;

  const unsigned short* Qg = Qb + ((size_t)bh * 1024 + q0) * 32;
  const unsigned short* Kg = Kb + (size_t)bh * 1024 * 32;
  const unsigned short* Vg = Vtb + (size_t)bh * 32 * 1024;
  const float* tg = tableT + (size_t)h * 4096;

  for (int i = tid; i < 3969; i += 512) th[i] = tg[i];
  bf16x8 qf = *(const bf16x8*)(Qg + (size_t)(w * 16 + n) * 32 + g * 8);
  __syncthreads();  // table ready — the only barrier

  f32x4 oacc[2];
  oacc[0] = (f32x4){0.f, 0.f, 0.f, 0.f};
  oacc[1] = (f32x4){0.f, 0.f, 0.f, 0.f};
  float m_run = -1e30f, l_run = 0.f;  // l_run g-partial, reduced at end

  int q = q0 + w * 16 + n;
  int tbase = (q >> 5) * 63 + (q & 31) + 1984;  // + (31*63+31)

  unsigned short* PwA = &Ps[0][w][0];
  unsigned short* PwB = &Ps[1][w][0];

  bf16x8 kfA[4], kfB[4];
#pragma unroll
  for (int mt = 0; mt < 4; mt++)
    kfA[mt] = *(const bf16x8*)(Kg + (size_t)(mt * 16 + n) * 32 + g * 8);

  auto half_step = [&](const bf16x8 (&kf)[4], int k0, unsigned short* Pw) {
    bf16x8 vf[4];
#pragma unroll
    for (int i = 0; i < 4; i++)
      vf[i] = *(const bf16x8*)(Vg + (size_t)((i & 1) * 16 + n) * 1024 + k0 +
                               (i >> 1) * 32 + g * 8);

    f32x4 s[4];
    __builtin_amdgcn_s_setprio(1);
#pragma unroll
    for (int mt = 0; mt < 4; mt++)
      s[mt] = __builtin_amdgcn_mfma_f32_16x16x32_bf16(
          kf[mt], qf, (f32x4){0.f, 0.f, 0.f, 0.f}, 0, 0, 0);
    __builtin_amdgcn_s_setprio(0);

#pragma unroll
    for (int mt = 0; mt < 4; mt++) {
      int kb = k0 + mt * 16 + g * 4;
      int ib = tbase - (kb >> 5) * 63 - (kb & 31);
      s[mt][0] += th[ib];
      s[mt][1] += th[ib - 1];
      s[mt][2] += th[ib - 2];
      s[mt][3] += th[ib - 3];
    }

    float mx = -1e30f;
#pragma unroll
    for (int mt = 0; mt < 4; mt++)
#pragma unroll
      for (int r = 0; r < 4; r++) mx = fmaxf(mx, s[mt][r]);
    mx = fmaxf(mx, __shfl_xor(mx, 16, 64));
    mx = fmaxf(mx, __shfl_xor(mx, 32, 64));
    // defer-max (T13): only rescale when the max actually moved by >8.
    // When skipped, P = exp(s - m_run) is bounded by e^8 — bf16-safe.
    if (!__all(mx <= m_run + 8.0f)) {
      float m_new = fmaxf(m_run, mx);
      float alpha = __expf(m_run - m_new);
      m_run = m_new;
      l_run *= alpha;
#pragma unroll
      for (int dt = 0; dt < 2; dt++)
#pragma unroll
        for (int r = 0; r < 4; r++) oacc[dt][r] *= alpha;
    }

    float ls = 0.f;
#pragma unroll
    for (int mt = 0; mt < 4; mt++) {
#pragma unroll
      for (int r = 0; r < 4; r++) {
        float p = __expf(s[mt][r] - m_run);
        s[mt][r] = p;
        ls += p;
      }
      u16x4 pk = {f2bf(s[mt][0]), f2bf(s[mt][1]), f2bf(s[mt][2]),
                  f2bf(s[mt][3])};
      *(u16x4*)(Pw + n * 68 + mt * 16 + g * 4) = pk;
    }
    l_run += ls;

    __builtin_amdgcn_s_setprio(1);
#pragma unroll
    for (int kt = 0; kt < 2; kt++) {
      bf16x8 pf = *(const bf16x8*)(Pw + n * 68 + kt * 32 + g * 8);
      oacc[0] = __builtin_amdgcn_mfma_f32_16x16x32_bf16(vf[kt * 2 + 0], pf,
                                                        oacc[0], 0, 0, 0);
      oacc[1] = __builtin_amdgcn_mfma_f32_16x16x32_bf16(vf[kt * 2 + 1], pf,
                                                        oacc[1], 0, 0, 0);
    }
    __builtin_amdgcn_s_setprio(0);
  };

  for (int tt = 0; tt < 8; tt++) {
    int k0 = tt * 128;
#pragma unroll
    for (int mt = 0; mt < 4; mt++)
      kfB[mt] = *(const bf16x8*)(Kg + (size_t)(k0 + 64 + mt * 16 + n) * 32 +
                                 g * 8);
    half_step(kfA, k0, PwA);
    if (tt < 7) {
#pragma unroll
      for (int mt = 0; mt < 4; mt++)
        kfA[mt] = *(const bf16x8*)(Kg + (size_t)(k0 + 128 + mt * 16 + n) * 32 +
                                   g * 8);
    }
    half_step(kfB, k0 + 64, PwB);
  }

  float l = l_run;
  l += __shfl_xor(l, 16, 64);
  l += __shfl_xor(l, 32, 64);
  float invl = 1.f / l;
  unsigned short* ob = out + ((size_t)(b * 1024 + q) * 256) + h * 32;
#pragma unroll
  for (int dt = 0; dt < 2; dt++) {
    u16x4 o4 = {f2bf(oacc[dt][0] * invl), f2bf(oacc[dt][1] * invl),
                f2bf(oacc[dt][2] * invl), f2bf(oacc[dt][3] * invl)};
    *(u16x4*)(ob + dt * 16 + g * 4) = o4;
  }
}

// ---------------------------------------------------------------------------
extern "C" void kernel_launch(void* const* d_in, const int* in_sizes, int n_in,
                              void* d_out, int out_size, void* d_ws, size_t ws_size,
                              hipStream_t stream) {
  const float* x         = (const float*)d_in[0];
  const float* w_embed   = (const float*)d_in[1];
  const float* b_embed   = (const float*)d_in[2];
  const float* cpb_w1    = (const float*)d_in[3];
  const float* cpb_b1    = (const float*)d_in[4];
  const float* cpb_w2    = (const float*)d_in[5];
  const float* w_qkv     = (const float*)d_in[6];
  const float* b_qkv     = (const float*)d_in[7];
  const float* w_proj    = (const float*)d_in[8];
  const float* b_proj    = (const float*)d_in[9];
  const float* w_unembed = (const float*)d_in[10];
  const float* b_unembed = (const float*)d_in[11];
  float* out = (float*)d_out;

  // workspace layout (~42.8 MB)
  char* w = (char*)d_ws;
  unsigned short* tok   = (unsigned short*)w; w += (size_t)8192 * 256 * 2;   //  4 MB
  unsigned short* wE    = (unsigned short*)w; w += (size_t)1048576 * 2;      //  2 MB
  unsigned short* wQ    = (unsigned short*)w; w += (size_t)196608 * 2;       // 384 KB
  unsigned short* wUt   = (unsigned short*)w; w += (size_t)1048576 * 2;      //  2 MB
  unsigned short* wPT   = (unsigned short*)w; w += (size_t)65536 * 2;        // 128 KB
  unsigned short* Wc    = (unsigned short*)w; w += (size_t)1048576 * 2;      //  2 MB
  float*          bc    = (float*)w;          w += (size_t)4096 * 4;         //  16 KB
  float*          tableT= (float*)w;          w += (size_t)32768 * 4;        // 128 KB
  float*          PART  = (float*)w;          w += (size_t)4 * 2097152 * 4;  // 32 MB

  // live-range aliases inside PART (embed partials dead once reduced):
  unsigned short* qkvB  = (unsigned short*)PART;                     // 12 MB
  unsigned short* attno = (unsigned short*)((char*)PART + 12582912); //  4 MB
  unsigned short* Qb  = qkvB;
  unsigned short* Kb  = qkvB + 2097152;
  unsigned short* Vtb = qkvB + 2 * 2097152;

  // ---- prep (all weight cvt/transpose + RPE MLP + bc), one kernel ----
  prep_kernel<<<1728, 256, 0, stream>>>(
      w_embed, w_qkv, w_unembed, w_proj, cpb_w1, cpb_b1, cpb_w2, b_proj,
      b_unembed, wE, wQ, wUt, wPT, tableT, bc);

  // ---- Wc = wUt @ wPT^T  (folded proj+unembed weights, bf16) ----
  gemm_mfma_kernel<1><<<dim3(2, 32), 256, 0, stream>>>(
      wUt, wPT, nullptr, Wc, 4096, 256, 256, 256, 256, 256);

  // ---- embed: 2-deep direct-A counted-vmcnt split-K x4 -> reduce -> tok ----
  gemm_embed_kernel<<<512, 256, 0, stream>>>(x, wE, PART);
  splitk_reduce_kernel<4><<<1024, 256, 0, stream>>>(PART, b_embed, tok);

  // ---- qkv + fused split/scale/transpose into Qb/Kb/Vtb ----
  gemm_mfma_kernel<3><<<dim3(6, 64), 256, 0, stream>>>(
      tok, wQ, b_qkv, qkvB, 8192, 768, 256, 256, 256, 0);

  // ---- attention (barrier-free, rolled 8x2, defer-max) ----
  attn_mfma_kernel<<<512, 512, 0, stream>>>(Qb, Kb, Vtb, tableT, attno);

  // ---- fused proj+unembed + col2im: out = col2im(attno @ Wc^T + bc) ----
  gemm_mfma_kernel<2><<<dim3(32, 64), 256, 0, stream>>>(
      attno, Wc, bc, out, 8192, 4096, 256, 256, 256, 0);
}